// Round 1
// 142.521 us; speedup vs baseline: 1.0424x; 1.0424x over previous
//
#include <hip/hip_runtime.h>
#include <math.h>

#define NPTS 4096
#define LDA  264          // bf16 row stride (16B-aligned, conflict-benign)
// LDS regions (bytes)
#define S_R1  0           // bf16 [67][LDA]: xT -> x1 -> xs -> y
#define S_R3  35376       // bf16 [64][LDA]: delta ; later f32 Ct[32][257]
#define S_BML 69168       // f32 [64][20]
#define S_CML 74288       // f32 [64][20]
#define SMEM_SZ 79408

typedef __bf16 bf16x8 __attribute__((ext_vector_type(8)));
typedef __bf16 bf16x4 __attribute__((ext_vector_type(4)));
typedef float  f32x4  __attribute__((ext_vector_type(4)));

__device__ __forceinline__ float sigmoidf_(float v) { return 1.f / (1.f + expf(-v)); }

// ===== K0: one-shot fp32->bf16 for w_in, w_out, Bw, Cw
__global__ __launch_bounds__(256) void k_prep(const float* __restrict__ w_in,
                                              const float* __restrict__ w_out,
                                              const float* __restrict__ Bw,
                                              const float* __restrict__ Cw,
                                              __bf16* __restrict__ wbi,
                                              __bf16* __restrict__ wbo,
                                              __bf16* __restrict__ wbB,
                                              __bf16* __restrict__ wbC) {
  int i = blockIdx.x * 256 + threadIdx.x;   // float4 index, 51200 total
  const float* src; __bf16* dst; int off;
  if (i < 32768)      { src = w_in;  dst = wbi; off = i; }
  else if (i < 49152) { src = w_out; dst = wbo; off = i - 32768; }
  else if (i < 50176) { src = Bw;    dst = wbB; off = i - 49152; }
  else                { src = Cw;    dst = wbC; off = i - 50176; }
  float4 v = *(const float4*)&src[off << 2];
  bf16x4 p;
  p[0] = (__bf16)v.x; p[1] = (__bf16)v.y; p[2] = (__bf16)v.z; p[3] = (__bf16)v.w;
  *(bf16x4*)&dst[off << 2] = p;
}

// ===== K1: fully fused block. grid (128, 4), 512 threads, 79.4 KB dyn LDS (2 blk/CU).
// Per block: transpose halo -> in_proj (delta pass, x1 pass) -> conv+silu in place ->
// B/C proj -> 32 warm + 32 live scan -> out_proj -> residual + LN -> store.
__global__ __launch_bounds__(512, 4) void k_mega(const float* __restrict__ x,
                                                 const __bf16* __restrict__ wbi,
                                                 const float* __restrict__ b_in,
                                                 const float* __restrict__ wconv,
                                                 const float* __restrict__ bconv,
                                                 const __bf16* __restrict__ wbB,
                                                 const __bf16* __restrict__ wbC,
                                                 const float* __restrict__ A_log,
                                                 const float* __restrict__ Dsk,
                                                 const __bf16* __restrict__ wbo,
                                                 const float* __restrict__ b_out,
                                                 const float* __restrict__ gamma,
                                                 const float* __restrict__ beta,
                                                 float* __restrict__ out) {
  extern __shared__ unsigned char smem[];
  __bf16* R1  = (__bf16*)(smem + S_R1);
  __bf16* bdt = (__bf16*)(smem + S_R3);
  float*  Bml = (float*) (smem + S_BML);
  float*  Cml = (float*) (smem + S_CML);
  float*  Ct  = (float*) (smem + S_R3);   // aliases bdt (dead after scan)

  const int tid = threadIdx.x, lane = tid & 63, w = tid >> 6;
  const int b = blockIdx.y, t0 = blockIdx.x << 5;
  const int mrow = lane & 15, klane = (lane >> 4) << 3;
  const int r4 = (lane >> 4) << 2;

  // ---- P1: transpose x[b, :, t0-35 .. t0+31] -> R1 rows 0..66 (row i <-> t = t0-35+i)
  {
    const int c = tid >> 1;
    const size_t xrow = (size_t)(b * 256 + c) * NPTS;
    #pragma unroll
    for (int r = 0; r < 8; ++r) {
      int q = (tid & 1) + (r << 1);
      int t = t0 - 32 + (q << 2);
      float4 v = make_float4(0.f, 0.f, 0.f, 0.f);
      if (t >= 0) v = *(const float4*)&x[xrow + t];
      int i0 = 3 + (q << 2);
      R1[(i0 + 0) * LDA + c] = (__bf16)v.x;
      R1[(i0 + 1) * LDA + c] = (__bf16)v.y;
      R1[(i0 + 2) * LDA + c] = (__bf16)v.z;
      R1[(i0 + 3) * LDA + c] = (__bf16)v.w;
    }
    if (tid < 256) {   // head rows 0..2 (t = t0-35..t0-33)
      int t = t0 - 36;
      float4 v = make_float4(0.f, 0.f, 0.f, 0.f);
      if (t >= 0) v = *(const float4*)&x[(size_t)(b * 256 + tid) * NPTS + t];
      R1[0 * LDA + tid] = (__bf16)v.y;
      R1[1 * LDA + tid] = (__bf16)v.z;
      R1[2 * LDA + tid] = (__bf16)v.w;
    }
  }
  __syncthreads();

  // ---- P2: delta = sigmoid(Wz.x + bz): M 256..511, n-tiles {3,19,35,51} -> bdt[64][LDA]
  {
    f32x4 acc[2][4] = {};
    const int mb = 256 + (w << 5);
    for (int k0 = 0; k0 < 256; k0 += 32) {
      bf16x8 af[2], bx[4];
      #pragma unroll
      for (int mi = 0; mi < 2; ++mi)
        af[mi] = *(const bf16x8*)&wbi[((size_t)(mb + (mi << 4) + mrow)) * 256 + k0 + klane];
      #pragma unroll
      for (int ni = 0; ni < 4; ++ni)
        bx[ni] = *(bf16x8*)&R1[(3 + (ni << 4) + mrow) * LDA + k0 + klane];
      #pragma unroll
      for (int mi = 0; mi < 2; ++mi)
        #pragma unroll
        for (int ni = 0; ni < 4; ++ni)
          acc[mi][ni] = __builtin_amdgcn_mfma_f32_16x16x32_bf16(af[mi], bx[ni], acc[mi][ni], 0, 0, 0);
    }
    #pragma unroll
    for (int mi = 0; mi < 2; ++mi) {
      int d = (w << 5) + (mi << 4) + r4;
      float4 bi = *(const float4*)&b_in[256 + d];
      float bia[4] = {bi.x, bi.y, bi.z, bi.w};
      #pragma unroll
      for (int ni = 0; ni < 4; ++ni) {
        int j = (ni << 4) + mrow;                 // row j <-> t = t0-32+j
        bool ok = (t0 - 32 + j) >= 0;
        bf16x4 p;
        #pragma unroll
        for (int rg = 0; rg < 4; ++rg)
          p[rg] = ok ? (__bf16)sigmoidf_(acc[mi][ni][rg] + bia[rg]) : (__bf16)0.f;
        *(bf16x4*)&bdt[j * LDA + d] = p;
      }
    }
  }

  // ---- P3: x1 = Wx.x + bx: M 0..255, n-tiles {0,16,32,48,51} -> R1 (in place after barrier)
  {
    f32x4 acc[2][5] = {};
    const int mb = w << 5;
    for (int k0 = 0; k0 < 256; k0 += 32) {
      bf16x8 af[2], bx[5];
      #pragma unroll
      for (int mi = 0; mi < 2; ++mi)
        af[mi] = *(const bf16x8*)&wbi[((size_t)(mb + (mi << 4) + mrow)) * 256 + k0 + klane];
      bx[0] = *(bf16x8*)&R1[( 0 + mrow) * LDA + k0 + klane];
      bx[1] = *(bf16x8*)&R1[(16 + mrow) * LDA + k0 + klane];
      bx[2] = *(bf16x8*)&R1[(32 + mrow) * LDA + k0 + klane];
      bx[3] = *(bf16x8*)&R1[(48 + mrow) * LDA + k0 + klane];
      bx[4] = *(bf16x8*)&R1[(51 + mrow) * LDA + k0 + klane];
      #pragma unroll
      for (int mi = 0; mi < 2; ++mi)
        #pragma unroll
        for (int ni = 0; ni < 5; ++ni)
          acc[mi][ni] = __builtin_amdgcn_mfma_f32_16x16x32_bf16(af[mi], bx[ni], acc[mi][ni], 0, 0, 0);
    }
    __syncthreads();   // all xT reads done -> R1 writable
    #pragma unroll
    for (int mi = 0; mi < 2; ++mi) {
      int d = (w << 5) + (mi << 4) + r4;
      float4 bi = *(const float4*)&b_in[d];
      float bia[4] = {bi.x, bi.y, bi.z, bi.w};
      const int n0s[5] = {0, 16, 32, 48, 51};
      #pragma unroll
      for (int ni = 0; ni < 5; ++ni) {
        int i = n0s[ni] + mrow;                   // rows 51..63 double-written, same value
        bool ok = (t0 - 35 + i) >= 0;
        bf16x4 p;
        #pragma unroll
        for (int rg = 0; rg < 4; ++rg) {
          float v = acc[mi][ni][rg] + bia[rg];
          p[rg] = ok ? (__bf16)v : (__bf16)0.f;
        }
        *(bf16x4*)&R1[i * LDA + d] = p;
      }
    }
  }
  __syncthreads();

  // ---- P4: conv + silu, in place with -3 row stagger: xs row j overwrites x1 row j
  {
    const int d = tid & 255, half = tid >> 8;
    const int j0 = half << 5;
    const float4 wc = *(const float4*)&wconv[d << 2];
    const float bcv = bconv[d];
    float m3 = (float)R1[(j0 + 0) * LDA + d];
    float m2 = (float)R1[(j0 + 1) * LDA + d];
    float m1 = (float)R1[(j0 + 2) * LDA + d];
    float d0 = 0.f, d1 = 0.f, d2 = 0.f;   // upper half defers rows 32..34 (seam race)
    #pragma unroll
    for (int i2 = 0; i2 < 32; ++i2) {
      float xc = (float)R1[(j0 + i2 + 3) * LDA + d];
      float cv = fmaf(wc.x, m3, fmaf(wc.y, m2, fmaf(wc.z, m1, fmaf(wc.w, xc, bcv))));
      float sv = cv * sigmoidf_(cv);
      if (half && i2 == 0)      d0 = sv;
      else if (half && i2 == 1) d1 = sv;
      else if (half && i2 == 2) d2 = sv;
      else R1[(j0 + i2) * LDA + d] = (__bf16)sv;
      m3 = m2; m2 = m1; m1 = xc;
    }
    __syncthreads();
    if (half) {
      R1[32 * LDA + d] = (__bf16)d0;
      R1[33 * LDA + d] = (__bf16)d1;
      R1[34 * LDA + d] = (__bf16)d2;
    }
  }
  __syncthreads();

  // ---- P5: B/C projection, all 8 waves (w&1 = B/C, w>>1 = n-tile)
  {
    const int mat = w & 1, n0 = (w >> 1) << 4;
    const __bf16* Wr = mat ? wbC : wbB;
    f32x4 acc = {};
    for (int k0 = 0; k0 < 256; k0 += 32) {
      bf16x8 av = *(const bf16x8*)&Wr[mrow * 256 + k0 + klane];
      bf16x8 bv = *(bf16x8*)&R1[(n0 + mrow) * LDA + k0 + klane];
      acc = __builtin_amdgcn_mfma_f32_16x16x32_bf16(av, bv, acc, 0, 0, 0);
    }
    float* dst = mat ? Cml : Bml;
    int j = n0 + mrow;
    #pragma unroll
    for (int rg = 0; rg < 4; ++rg)
      dst[j * 20 + r4 + rg] = acc[rg];
  }
  __syncthreads();

  // ---- P6: scan — 32 warm steps (h only), 32 live steps (y -> R1 in place)
  const int ds = tid >> 1, sh = (tid & 1) << 3;
  float a[8], h[8];
  {
    float4 a0 = *(const float4*)&A_log[(ds << 4) + sh];
    float4 a1 = *(const float4*)&A_log[(ds << 4) + sh + 4];
    a[0] = -expf(a0.x); a[1] = -expf(a0.y); a[2] = -expf(a0.z); a[3] = -expf(a0.w);
    a[4] = -expf(a1.x); a[5] = -expf(a1.y); a[6] = -expf(a1.z); a[7] = -expf(a1.w);
  }
  #pragma unroll
  for (int s = 0; s < 8; ++s) h[s] = 0.f;
  const float Dv = Dsk[ds];
  #pragma unroll
  for (int j = 0; j < 32; ++j) {
    float u = (float)bdt[j * LDA + ds];
    float4 b0 = *(float4*)&Bml[j * 20 + sh];
    float4 b1 = *(float4*)&Bml[j * 20 + sh + 4];
    h[0] = fmaf(a[0], h[0], u * b0.x);
    h[1] = fmaf(a[1], h[1], u * b0.y);
    h[2] = fmaf(a[2], h[2], u * b0.z);
    h[3] = fmaf(a[3], h[3], u * b0.w);
    h[4] = fmaf(a[4], h[4], u * b1.x);
    h[5] = fmaf(a[5], h[5], u * b1.y);
    h[6] = fmaf(a[6], h[6], u * b1.z);
    h[7] = fmaf(a[7], h[7], u * b1.w);
  }
  #pragma unroll
  for (int j = 32; j < 64; ++j) {
    float u = (float)bdt[j * LDA + ds];
    float4 b0 = *(float4*)&Bml[j * 20 + sh];
    float4 b1 = *(float4*)&Bml[j * 20 + sh + 4];
    float4 c0 = *(float4*)&Cml[j * 20 + sh];
    float4 c1 = *(float4*)&Cml[j * 20 + sh + 4];
    h[0] = fmaf(a[0], h[0], u * b0.x);
    h[1] = fmaf(a[1], h[1], u * b0.y);
    h[2] = fmaf(a[2], h[2], u * b0.z);
    h[3] = fmaf(a[3], h[3], u * b0.w);
    h[4] = fmaf(a[4], h[4], u * b1.x);
    h[5] = fmaf(a[5], h[5], u * b1.y);
    h[6] = fmaf(a[6], h[6], u * b1.z);
    h[7] = fmaf(a[7], h[7], u * b1.w);
    float yv = h[0] * c0.x + h[1] * c0.y + h[2] * c0.z + h[3] * c0.w
             + h[4] * c1.x + h[5] * c1.y + h[6] * c1.z + h[7] * c1.w;
    yv += __shfl_xor(yv, 1);
    if ((tid & 1) == 0) {
      float xv = (float)R1[j * LDA + ds];
      R1[j * LDA + ds] = (__bf16)fmaf(Dv, xv, yv);
    }
  }
  __syncthreads();

  // ---- P7: out_proj MFMA on y (R1 rows 32..63) -> Ct (aliases dead bdt)
  {
    const int o0w = w << 5;
    f32x4 acc[2][2] = {};
    for (int k0 = 0; k0 < 256; k0 += 32) {
      bf16x8 af[2], bx[2];
      #pragma unroll
      for (int mi = 0; mi < 2; ++mi)
        af[mi] = *(const bf16x8*)&wbo[((size_t)(o0w + (mi << 4) + mrow)) * 256 + k0 + klane];
      #pragma unroll
      for (int ni = 0; ni < 2; ++ni)
        bx[ni] = *(bf16x8*)&R1[(32 + (ni << 4) + mrow) * LDA + k0 + klane];
      #pragma unroll
      for (int mi = 0; mi < 2; ++mi)
        #pragma unroll
        for (int ni = 0; ni < 2; ++ni)
          acc[mi][ni] = __builtin_amdgcn_mfma_f32_16x16x32_bf16(af[mi], bx[ni], acc[mi][ni], 0, 0, 0);
    }
    #pragma unroll
    for (int mi = 0; mi < 2; ++mi)
      #pragma unroll
      for (int ni = 0; ni < 2; ++ni) {
        int t = (ni << 4) + mrow;
        int o = o0w + (mi << 4) + r4;
        #pragma unroll
        for (int rg = 0; rg < 4; ++rg)
          Ct[t * 257 + o + rg] = acc[mi][ni][rg];
      }
  }
  __syncthreads();

  // ---- P8: residual + bias, LayerNorm over C, transposed store
  #pragma unroll
  for (int r = 0; r < 4; ++r) {
    int idx = (r << 9) + tid;
    int c = idx >> 3, t4 = (idx & 7) << 2;
    float4 xv = *(const float4*)&x[((size_t)(b * 256 + c)) * NPTS + t0 + t4];
    float bo = b_out[c];
    Ct[(t4 + 0) * 257 + c] += xv.x + bo;
    Ct[(t4 + 1) * 257 + c] += xv.y + bo;
    Ct[(t4 + 2) * 257 + c] += xv.z + bo;
    Ct[(t4 + 3) * 257 + c] += xv.w + bo;
  }
  float g[4], be[4];
  #pragma unroll
  for (int j = 0; j < 4; ++j) {
    g[j] = gamma[lane + 64 * j];
    be[j] = beta[lane + 64 * j];
  }
  __syncthreads();
  #pragma unroll
  for (int rr = 0; rr < 4; ++rr) {
    int t = (w << 2) + rr;
    float v[4];
    float sum = 0.f, sq = 0.f;
    #pragma unroll
    for (int j = 0; j < 4; ++j) {
      v[j] = Ct[t * 257 + lane + 64 * j];
      sum += v[j];
      sq += v[j] * v[j];
    }
    #pragma unroll
    for (int m = 1; m < 64; m <<= 1) {
      sum += __shfl_xor(sum, m);
      sq += __shfl_xor(sq, m);
    }
    float mean = sum * (1.f / 256.f);
    float var = sq * (1.f / 256.f) - mean * mean;
    float rstd = rsqrtf(var + 1e-5f);
    #pragma unroll
    for (int j = 0; j < 4; ++j)
      Ct[t * 257 + lane + 64 * j] = (v[j] - mean) * rstd * g[j] + be[j];
  }
  __syncthreads();
  #pragma unroll
  for (int p = 0; p < 16; ++p) {
    int c = (p << 4) + (tid >> 5);
    int t = tid & 31;
    out[((size_t)(b * 256 + c)) * NPTS + t0 + t] = Ct[t * 257 + c];
  }
}

extern "C" void kernel_launch(void* const* d_in, const int* in_sizes, int n_in,
                              void* d_out, int out_size, void* d_ws, size_t ws_size,
                              hipStream_t stream) {
  const float* x     = (const float*)d_in[0];
  const float* w_in  = (const float*)d_in[1];
  const float* b_in  = (const float*)d_in[2];
  const float* wconv = (const float*)d_in[3];
  const float* bconv = (const float*)d_in[4];
  const float* A_log = (const float*)d_in[5];
  const float* Dsk   = (const float*)d_in[6];
  const float* Bw    = (const float*)d_in[7];
  const float* Cw    = (const float*)d_in[8];
  const float* w_out = (const float*)d_in[9];
  const float* b_out = (const float*)d_in[10];
  const float* gamma = (const float*)d_in[11];
  const float* beta  = (const float*)d_in[12];
  float* ws = (float*)d_ws;
  __bf16* wbi = (__bf16*)(ws + 0);        // [512][256]
  __bf16* wbo = (__bf16*)(ws + 65536);    // [256][256]
  __bf16* wbB = (__bf16*)(ws + 98304);    // [16][256]
  __bf16* wbC = (__bf16*)(ws + 100352);   // [16][256]
  float* out = (float*)d_out;

  static int s_attr = 0;
  if (!s_attr) {
    hipFuncSetAttribute(reinterpret_cast<const void*>(k_mega),
                        hipFuncAttributeMaxDynamicSharedMemorySize, SMEM_SZ);
    s_attr = 1;
  }
  k_prep<<<200, 256, 0, stream>>>(w_in, w_out, Bw, Cw, wbi, wbo, wbB, wbC);
  k_mega<<<dim3(128, 4), 512, SMEM_SZ, stream>>>(x, wbi, b_in, wconv, bconv, wbB, wbC,
                                                 A_log, Dsk, wbo, b_out, gamma, beta, out);
}

// Round 2
// 138.786 us; speedup vs baseline: 1.0704x; 1.0269x over previous
//
#include <hip/hip_runtime.h>
#include <math.h>

#define NPTS 4096
#define LDA  264          // bf16 row stride (16B-aligned, conflict-benign)
// LDS regions (bytes)
#define S_R1  0           // bf16 [67][LDA]: xT -> x1 -> xs -> y
#define S_R3  35376       // bf16 [64][LDA]: delta ; later f32 Ct[32][257]
#define S_BML 69168       // f32 [64][20]
#define S_CML 74288       // f32 [64][20]
#define SMEM_SZ 79408

typedef __bf16 bf16x8 __attribute__((ext_vector_type(8)));
typedef __bf16 bf16x4 __attribute__((ext_vector_type(4)));
typedef float  f32x4  __attribute__((ext_vector_type(4)));

// fast sigmoid: v_exp + fast rcp (~5 instr vs ~40 for precise libm path)
__device__ __forceinline__ float sigmoidf_(float v) {
  return __fdividef(1.f, 1.f + __expf(-v));
}

// ===== K0: one-shot fp32->bf16 for w_in, w_out, Bw, Cw; plus A = -exp(A_log) table
__global__ __launch_bounds__(256) void k_prep(const float* __restrict__ w_in,
                                              const float* __restrict__ w_out,
                                              const float* __restrict__ Bw,
                                              const float* __restrict__ Cw,
                                              const float* __restrict__ A_log,
                                              __bf16* __restrict__ wbi,
                                              __bf16* __restrict__ wbo,
                                              __bf16* __restrict__ wbB,
                                              __bf16* __restrict__ wbC,
                                              float* __restrict__ Af) {
  int i = blockIdx.x * 256 + threadIdx.x;   // float4 index, 52224 total
  if (i >= 51200) {                         // A table: 1024 float4
    int j = (i - 51200) << 2;
    float4 v = *(const float4*)&A_log[j];
    float4 o;
    o.x = -__expf(v.x); o.y = -__expf(v.y); o.z = -__expf(v.z); o.w = -__expf(v.w);
    *(float4*)&Af[j] = o;
    return;
  }
  const float* src; __bf16* dst; int off;
  if (i < 32768)      { src = w_in;  dst = wbi; off = i; }
  else if (i < 49152) { src = w_out; dst = wbo; off = i - 32768; }
  else if (i < 50176) { src = Bw;    dst = wbB; off = i - 49152; }
  else                { src = Cw;    dst = wbC; off = i - 50176; }
  float4 v = *(const float4*)&src[off << 2];
  bf16x4 p;
  p[0] = (__bf16)v.x; p[1] = (__bf16)v.y; p[2] = (__bf16)v.z; p[3] = (__bf16)v.w;
  *(bf16x4*)&dst[off << 2] = p;
}

// ===== K1: fully fused block. grid (128, 4), 512 threads, 79.4 KB dyn LDS (2 blk/CU).
__global__ __launch_bounds__(512, 4) void k_mega(const float* __restrict__ x,
                                                 const __bf16* __restrict__ wbi,
                                                 const float* __restrict__ b_in,
                                                 const float* __restrict__ wconv,
                                                 const float* __restrict__ bconv,
                                                 const __bf16* __restrict__ wbB,
                                                 const __bf16* __restrict__ wbC,
                                                 const float* __restrict__ Af,
                                                 const float* __restrict__ Dsk,
                                                 const __bf16* __restrict__ wbo,
                                                 const float* __restrict__ b_out,
                                                 const float* __restrict__ gamma,
                                                 const float* __restrict__ beta,
                                                 float* __restrict__ out) {
  extern __shared__ unsigned char smem[];
  __bf16* R1  = (__bf16*)(smem + S_R1);
  __bf16* bdt = (__bf16*)(smem + S_R3);
  float*  Bml = (float*) (smem + S_BML);
  float*  Cml = (float*) (smem + S_CML);
  float*  Ct  = (float*) (smem + S_R3);   // aliases bdt (dead after scan)

  const int tid = threadIdx.x, lane = tid & 63, w = tid >> 6;
  const int b = blockIdx.y, t0 = blockIdx.x << 5;
  const int mrow = lane & 15, klane = (lane >> 4) << 3;
  const int r4 = (lane >> 4) << 2;

  // ---- P1: transpose x[b, :, t0-35 .. t0+31] -> R1 rows 0..66 (row i <-> t = t0-35+i)
  {
    const int c = tid >> 1;
    const size_t xrow = (size_t)(b * 256 + c) * NPTS;
    #pragma unroll
    for (int r = 0; r < 8; ++r) {
      int q = (tid & 1) + (r << 1);
      int t = t0 - 32 + (q << 2);
      float4 v = make_float4(0.f, 0.f, 0.f, 0.f);
      if (t >= 0) v = *(const float4*)&x[xrow + t];
      int i0 = 3 + (q << 2);
      R1[(i0 + 0) * LDA + c] = (__bf16)v.x;
      R1[(i0 + 1) * LDA + c] = (__bf16)v.y;
      R1[(i0 + 2) * LDA + c] = (__bf16)v.z;
      R1[(i0 + 3) * LDA + c] = (__bf16)v.w;
    }
    if (tid < 256) {   // head rows 0..2 (t = t0-35..t0-33)
      int t = t0 - 36;
      float4 v = make_float4(0.f, 0.f, 0.f, 0.f);
      if (t >= 0) v = *(const float4*)&x[(size_t)(b * 256 + tid) * NPTS + t];
      R1[0 * LDA + tid] = (__bf16)v.y;
      R1[1 * LDA + tid] = (__bf16)v.z;
      R1[2 * LDA + tid] = (__bf16)v.w;
    }
  }
  __syncthreads();

  // ---- P2: delta = sigmoid(Wz.x + bz): M 256..511, n-tiles {3,19,35,51} -> bdt[64][LDA]
  {
    f32x4 acc[2][4] = {};
    const int mb = 256 + (w << 5);
    const __bf16* w0 = &wbi[(size_t)(mb + mrow) * 256 + klane];
    const __bf16* w1 = &wbi[(size_t)(mb + 16 + mrow) * 256 + klane];
    bf16x8 af0n = *(const bf16x8*)&w0[0];
    bf16x8 af1n = *(const bf16x8*)&w1[0];
    bf16x8 bxn[4];
    #pragma unroll
    for (int ni = 0; ni < 4; ++ni)
      bxn[ni] = *(bf16x8*)&R1[(3 + (ni << 4) + mrow) * LDA + klane];
    for (int k0 = 0; k0 < 256; k0 += 32) {
      bf16x8 af0 = af0n, af1 = af1n, bx[4];
      #pragma unroll
      for (int ni = 0; ni < 4; ++ni) bx[ni] = bxn[ni];
      int kn = (k0 + 32) & 255;
      af0n = *(const bf16x8*)&w0[kn];
      af1n = *(const bf16x8*)&w1[kn];
      #pragma unroll
      for (int ni = 0; ni < 4; ++ni)
        bxn[ni] = *(bf16x8*)&R1[(3 + (ni << 4) + mrow) * LDA + kn + klane];
      #pragma unroll
      for (int ni = 0; ni < 4; ++ni) {
        acc[0][ni] = __builtin_amdgcn_mfma_f32_16x16x32_bf16(af0, bx[ni], acc[0][ni], 0, 0, 0);
        acc[1][ni] = __builtin_amdgcn_mfma_f32_16x16x32_bf16(af1, bx[ni], acc[1][ni], 0, 0, 0);
      }
    }
    #pragma unroll
    for (int mi = 0; mi < 2; ++mi) {
      int d = (w << 5) + (mi << 4) + r4;
      float4 bi = *(const float4*)&b_in[256 + d];
      float bia[4] = {bi.x, bi.y, bi.z, bi.w};
      #pragma unroll
      for (int ni = 0; ni < 4; ++ni) {
        int j = (ni << 4) + mrow;                 // row j <-> t = t0-32+j
        bool ok = (t0 - 32 + j) >= 0;
        bf16x4 p;
        #pragma unroll
        for (int rg = 0; rg < 4; ++rg)
          p[rg] = ok ? (__bf16)sigmoidf_(acc[mi][ni][rg] + bia[rg]) : (__bf16)0.f;
        *(bf16x4*)&bdt[j * LDA + d] = p;
      }
    }
  }

  // ---- P3: x1 = Wx.x + bx: M 0..255, n-tiles {0,16,32,48,51} -> R1 (in place after barrier)
  {
    f32x4 acc[2][5] = {};
    const int mb = w << 5;
    const __bf16* w0 = &wbi[(size_t)(mb + mrow) * 256 + klane];
    const __bf16* w1 = &wbi[(size_t)(mb + 16 + mrow) * 256 + klane];
    bf16x8 af0n = *(const bf16x8*)&w0[0];
    bf16x8 af1n = *(const bf16x8*)&w1[0];
    const int n0s[5] = {0, 16, 32, 48, 51};
    for (int k0 = 0; k0 < 256; k0 += 32) {
      bf16x8 af0 = af0n, af1 = af1n, bx[5];
      int kn = (k0 + 32) & 255;
      af0n = *(const bf16x8*)&w0[kn];
      af1n = *(const bf16x8*)&w1[kn];
      #pragma unroll
      for (int ni = 0; ni < 5; ++ni)
        bx[ni] = *(bf16x8*)&R1[(n0s[ni] + mrow) * LDA + k0 + klane];
      #pragma unroll
      for (int ni = 0; ni < 5; ++ni) {
        acc[0][ni] = __builtin_amdgcn_mfma_f32_16x16x32_bf16(af0, bx[ni], acc[0][ni], 0, 0, 0);
        acc[1][ni] = __builtin_amdgcn_mfma_f32_16x16x32_bf16(af1, bx[ni], acc[1][ni], 0, 0, 0);
      }
    }
    __syncthreads();   // all xT reads done -> R1 writable
    #pragma unroll
    for (int mi = 0; mi < 2; ++mi) {
      int d = (w << 5) + (mi << 4) + r4;
      float4 bi = *(const float4*)&b_in[d];
      float bia[4] = {bi.x, bi.y, bi.z, bi.w};
      #pragma unroll
      for (int ni = 0; ni < 5; ++ni) {
        int i = n0s[ni] + mrow;                   // rows 51..63 double-written, same value
        bool ok = (t0 - 35 + i) >= 0;
        bf16x4 p;
        #pragma unroll
        for (int rg = 0; rg < 4; ++rg) {
          float v = acc[mi][ni][rg] + bia[rg];
          p[rg] = ok ? (__bf16)v : (__bf16)0.f;
        }
        *(bf16x4*)&R1[i * LDA + d] = p;
      }
    }
  }
  __syncthreads();

  // ---- P4: conv + silu, in place with -3 row stagger, depth-1 prefetch of x window
  {
    const int d = tid & 255, half = tid >> 8;
    const int j0 = half << 5;
    const float4 wc = *(const float4*)&wconv[d << 2];
    const float bcv = bconv[d];
    float m3 = (float)R1[(j0 + 0) * LDA + d];
    float m2 = (float)R1[(j0 + 1) * LDA + d];
    float m1 = (float)R1[(j0 + 2) * LDA + d];
    float xc_n = (float)R1[(j0 + 3) * LDA + d];
    float d0 = 0.f, d1 = 0.f, d2 = 0.f;   // upper half defers rows 32..34 (seam race)
    #pragma unroll
    for (int i2 = 0; i2 < 32; ++i2) {
      float xc = xc_n;
      xc_n = (float)R1[(j0 + (i2 == 31 ? 34 : i2 + 4)) * LDA + d];  // folds at compile time
      float cv = fmaf(wc.x, m3, fmaf(wc.y, m2, fmaf(wc.z, m1, fmaf(wc.w, xc, bcv))));
      float sv = cv * sigmoidf_(cv);
      if (half && i2 == 0)      d0 = sv;
      else if (half && i2 == 1) d1 = sv;
      else if (half && i2 == 2) d2 = sv;
      else R1[(j0 + i2) * LDA + d] = (__bf16)sv;
      m3 = m2; m2 = m1; m1 = xc;
    }
    __syncthreads();
    if (half) {
      R1[32 * LDA + d] = (__bf16)d0;
      R1[33 * LDA + d] = (__bf16)d1;
      R1[34 * LDA + d] = (__bf16)d2;
    }
  }
  __syncthreads();

  // ---- P5: B/C projection, all 8 waves (w&1 = B/C, w>>1 = n-tile), prefetched
  {
    const int mat = w & 1, n0 = (w >> 1) << 4;
    const __bf16* Wr = (mat ? wbC : wbB) + mrow * 256 + klane;
    const __bf16* Br = &R1[(n0 + mrow) * LDA + klane];
    bf16x8 avn = *(const bf16x8*)&Wr[0];
    bf16x8 bvn = *(const bf16x8*)&Br[0];
    f32x4 acc = {};
    for (int k0 = 0; k0 < 256; k0 += 32) {
      bf16x8 av = avn, bv = bvn;
      int kn = (k0 + 32) & 255;
      avn = *(const bf16x8*)&Wr[kn];
      bvn = *(const bf16x8*)&Br[kn];
      acc = __builtin_amdgcn_mfma_f32_16x16x32_bf16(av, bv, acc, 0, 0, 0);
    }
    float* dst = mat ? Cml : Bml;           // D: row=m=s, col=n=t
    int j = n0 + mrow;
    #pragma unroll
    for (int rg = 0; rg < 4; ++rg)
      dst[j * 20 + r4 + rg] = acc[rg];
  }
  __syncthreads();

  // ---- P6: scan — 32 warm steps (h only), 32 live steps (y -> R1), depth-1 prefetch
  const int ds = tid >> 1, sh = (tid & 1) << 3;
  float a[8], h[8];
  {
    float4 a0 = *(const float4*)&Af[(ds << 4) + sh];
    float4 a1 = *(const float4*)&Af[(ds << 4) + sh + 4];
    a[0] = a0.x; a[1] = a0.y; a[2] = a0.z; a[3] = a0.w;
    a[4] = a1.x; a[5] = a1.y; a[6] = a1.z; a[7] = a1.w;
  }
  #pragma unroll
  for (int s = 0; s < 8; ++s) h[s] = 0.f;
  const float Dv = Dsk[ds];
  float u_n = (float)bdt[0 * LDA + ds];
  float4 b0_n = *(float4*)&Bml[0 * 20 + sh];
  float4 b1_n = *(float4*)&Bml[0 * 20 + sh + 4];
  #pragma unroll
  for (int j = 0; j < 32; ++j) {
    float u = u_n; float4 b0 = b0_n, b1 = b1_n;
    u_n = (float)bdt[(j + 1) * LDA + ds];          // j+1 <= 32: valid row
    b0_n = *(float4*)&Bml[(j + 1) * 20 + sh];
    b1_n = *(float4*)&Bml[(j + 1) * 20 + sh + 4];
    h[0] = fmaf(a[0], h[0], u * b0.x);
    h[1] = fmaf(a[1], h[1], u * b0.y);
    h[2] = fmaf(a[2], h[2], u * b0.z);
    h[3] = fmaf(a[3], h[3], u * b0.w);
    h[4] = fmaf(a[4], h[4], u * b1.x);
    h[5] = fmaf(a[5], h[5], u * b1.y);
    h[6] = fmaf(a[6], h[6], u * b1.z);
    h[7] = fmaf(a[7], h[7], u * b1.w);
  }
  {
    float4 c0_n = *(float4*)&Cml[32 * 20 + sh];
    float4 c1_n = *(float4*)&Cml[32 * 20 + sh + 4];
    #pragma unroll
    for (int j = 32; j < 64; ++j) {
      float u = u_n; float4 b0 = b0_n, b1 = b1_n, c0 = c0_n, c1 = c1_n;
      int jn = (j + 1) & 63;                       // j=63 wraps to row 0 (harmless)
      u_n = (float)bdt[jn * LDA + ds];
      b0_n = *(float4*)&Bml[jn * 20 + sh];
      b1_n = *(float4*)&Bml[jn * 20 + sh + 4];
      c0_n = *(float4*)&Cml[jn * 20 + sh];
      c1_n = *(float4*)&Cml[jn * 20 + sh + 4];
      h[0] = fmaf(a[0], h[0], u * b0.x);
      h[1] = fmaf(a[1], h[1], u * b0.y);
      h[2] = fmaf(a[2], h[2], u * b0.z);
      h[3] = fmaf(a[3], h[3], u * b0.w);
      h[4] = fmaf(a[4], h[4], u * b1.x);
      h[5] = fmaf(a[5], h[5], u * b1.y);
      h[6] = fmaf(a[6], h[6], u * b1.z);
      h[7] = fmaf(a[7], h[7], u * b1.w);
      float yv = h[0] * c0.x + h[1] * c0.y + h[2] * c0.z + h[3] * c0.w
               + h[4] * c1.x + h[5] * c1.y + h[6] * c1.z + h[7] * c1.w;
      yv += __shfl_xor(yv, 1);
      if ((tid & 1) == 0) {
        float xv = (float)R1[j * LDA + ds];
        R1[j * LDA + ds] = (__bf16)fmaf(Dv, xv, yv);
      }
    }
  }
  __syncthreads();

  // ---- P7: out_proj MFMA on y (R1 rows 32..63) -> Ct (aliases dead bdt; no interior barrier)
  float4 xv[4]; float bo4[4];
  {
    const int o0w = w << 5;
    const __bf16* w0 = &wbo[(size_t)(o0w + mrow) * 256 + klane];
    const __bf16* w1 = &wbo[(size_t)(o0w + 16 + mrow) * 256 + klane];
    bf16x8 af0n = *(const bf16x8*)&w0[0];
    bf16x8 af1n = *(const bf16x8*)&w1[0];
    bf16x8 bx0n = *(bf16x8*)&R1[(32 + mrow) * LDA + klane];
    bf16x8 bx1n = *(bf16x8*)&R1[(48 + mrow) * LDA + klane];
    f32x4 acc[2][2] = {};
    for (int k0 = 0; k0 < 256; k0 += 32) {
      bf16x8 af0 = af0n, af1 = af1n, bx0 = bx0n, bx1 = bx1n;
      int kn = (k0 + 32) & 255;
      af0n = *(const bf16x8*)&w0[kn];
      af1n = *(const bf16x8*)&w1[kn];
      bx0n = *(bf16x8*)&R1[(32 + mrow) * LDA + kn + klane];
      bx1n = *(bf16x8*)&R1[(48 + mrow) * LDA + kn + klane];
      acc[0][0] = __builtin_amdgcn_mfma_f32_16x16x32_bf16(af0, bx0, acc[0][0], 0, 0, 0);
      acc[0][1] = __builtin_amdgcn_mfma_f32_16x16x32_bf16(af0, bx1, acc[0][1], 0, 0, 0);
      acc[1][0] = __builtin_amdgcn_mfma_f32_16x16x32_bf16(af1, bx0, acc[1][0], 0, 0, 0);
      acc[1][1] = __builtin_amdgcn_mfma_f32_16x16x32_bf16(af1, bx1, acc[1][1], 0, 0, 0);
    }
    // issue the residual x-gather early: lands while Ct is being written
    #pragma unroll
    for (int r = 0; r < 4; ++r) {
      int idx = (r << 9) + tid;
      int c = idx >> 3, t4 = (idx & 7) << 2;
      xv[r] = *(const float4*)&x[((size_t)(b * 256 + c)) * NPTS + t0 + t4];
      bo4[r] = b_out[c];
    }
    #pragma unroll
    for (int mi = 0; mi < 2; ++mi)
      #pragma unroll
      for (int ni = 0; ni < 2; ++ni) {
        int t = (ni << 4) + mrow;
        int o = o0w + (mi << 4) + r4;
        #pragma unroll
        for (int rg = 0; rg < 4; ++rg)
          Ct[t * 257 + o + rg] = acc[mi][ni][rg];
      }
  }
  __syncthreads();

  // ---- P8: residual + bias, LayerNorm over C, transposed store
  #pragma unroll
  for (int r = 0; r < 4; ++r) {
    int idx = (r << 9) + tid;
    int c = idx >> 3, t4 = (idx & 7) << 2;
    Ct[(t4 + 0) * 257 + c] += xv[r].x + bo4[r];
    Ct[(t4 + 1) * 257 + c] += xv[r].y + bo4[r];
    Ct[(t4 + 2) * 257 + c] += xv[r].z + bo4[r];
    Ct[(t4 + 3) * 257 + c] += xv[r].w + bo4[r];
  }
  float g[4], be[4];
  #pragma unroll
  for (int j = 0; j < 4; ++j) {
    g[j] = gamma[lane + 64 * j];
    be[j] = beta[lane + 64 * j];
  }
  __syncthreads();
  #pragma unroll
  for (int rr = 0; rr < 4; ++rr) {
    int t = (w << 2) + rr;
    float v[4];
    float sum = 0.f, sq = 0.f;
    #pragma unroll
    for (int j = 0; j < 4; ++j) {
      v[j] = Ct[t * 257 + lane + 64 * j];
      sum += v[j];
      sq += v[j] * v[j];
    }
    #pragma unroll
    for (int m = 1; m < 64; m <<= 1) {
      sum += __shfl_xor(sum, m);
      sq += __shfl_xor(sq, m);
    }
    float mean = sum * (1.f / 256.f);
    float var = sq * (1.f / 256.f) - mean * mean;
    float rstd = rsqrtf(var + 1e-5f);
    #pragma unroll
    for (int j = 0; j < 4; ++j)
      Ct[t * 257 + lane + 64 * j] = (v[j] - mean) * rstd * g[j] + be[j];
  }
  __syncthreads();
  #pragma unroll
  for (int p = 0; p < 4; ++p) {
    int c = (p << 6) + (tid >> 3), t4 = (tid & 7) << 2;
    float4 o;
    o.x = Ct[(t4 + 0) * 257 + c];
    o.y = Ct[(t4 + 1) * 257 + c];
    o.z = Ct[(t4 + 2) * 257 + c];
    o.w = Ct[(t4 + 3) * 257 + c];
    *(float4*)&out[((size_t)(b * 256 + c)) * NPTS + t0 + t4] = o;
  }
}

extern "C" void kernel_launch(void* const* d_in, const int* in_sizes, int n_in,
                              void* d_out, int out_size, void* d_ws, size_t ws_size,
                              hipStream_t stream) {
  const float* x     = (const float*)d_in[0];
  const float* w_in  = (const float*)d_in[1];
  const float* b_in  = (const float*)d_in[2];
  const float* wconv = (const float*)d_in[3];
  const float* bconv = (const float*)d_in[4];
  const float* A_log = (const float*)d_in[5];
  const float* Dsk   = (const float*)d_in[6];
  const float* Bw    = (const float*)d_in[7];
  const float* Cw    = (const float*)d_in[8];
  const float* w_out = (const float*)d_in[9];
  const float* b_out = (const float*)d_in[10];
  const float* gamma = (const float*)d_in[11];
  const float* beta  = (const float*)d_in[12];
  float* ws = (float*)d_ws;
  __bf16* wbi = (__bf16*)(ws + 0);        // [512][256]
  __bf16* wbo = (__bf16*)(ws + 65536);    // [256][256]
  __bf16* wbB = (__bf16*)(ws + 98304);    // [16][256]
  __bf16* wbC = (__bf16*)(ws + 100352);   // [16][256]
  float*  Af  = ws + 102400;              // [256][16] = -exp(A_log)
  float* out = (float*)d_out;

  static int s_attr = 0;
  if (!s_attr) {
    hipFuncSetAttribute(reinterpret_cast<const void*>(k_mega),
                        hipFuncAttributeMaxDynamicSharedMemorySize, SMEM_SZ);
    s_attr = 1;
  }
  k_prep<<<204, 256, 0, stream>>>(w_in, w_out, Bw, Cw, A_log, wbi, wbo, wbB, wbC, Af);
  k_mega<<<dim3(128, 4), 512, SMEM_SZ, stream>>>(x, wbi, b_in, wconv, bconv, wbB, wbC,
                                                 Af, Dsk, wbo, b_out, gamma, beta, out);
}